// Round 1
// baseline (39.492 us; speedup 1.0000x reference)
//
#include <hip/hip_runtime.h>
#include <cmath>

#define N_NODES 1500
#define F_DIM 64

// Kernel 1: h1pb[i,k] = sum_f embed[i,f] * W1[f,k] + b1[k]
//           h2[i,k]   = sum_f embed[i,f] * W1[64+f,k]
// grid = N_NODES blocks, 128 threads (t<64 -> h1pb column, t>=64 -> h2 column)
__global__ void pg_compute_h(const float* __restrict__ embed,
                             const float* __restrict__ W1,
                             const float* __restrict__ b1,
                             float* __restrict__ h1pb,
                             float* __restrict__ h2) {
    const int i = blockIdx.x;
    const int t = threadIdx.x;      // 0..127
    const int k = t & 63;
    const int half = t >> 6;

    __shared__ float emb_s[64];
    if (t < 64) emb_s[t] = embed[i * 64 + t];
    __syncthreads();

    const float* wcol = W1 + (half * 64) * 64 + k;   // column k of W1 half
    float acc = (half == 0) ? b1[k] : 0.0f;
#pragma unroll
    for (int f = 0; f < 64; ++f) {
        acc = fmaf(emb_s[f], wcol[f * 64], acc);
    }
    if (half == 0) h1pb[i * 64 + k] = acc;
    else           h2[i * 64 + k]  = acc;
}

// Kernel 2: one 64-lane wave per edge; lane = hidden index k.
__global__ void pg_edge_kernel(const int* __restrict__ e0,
                               const int* __restrict__ e1,
                               const float* __restrict__ noise,
                               const float* __restrict__ tmp_p,
                               const float* __restrict__ W2,
                               const float* __restrict__ b2,
                               const float* __restrict__ h1pb,
                               const float* __restrict__ h2,
                               float* __restrict__ out,
                               int E) {
    const int wave = (int)((blockIdx.x * blockDim.x + threadIdx.x) >> 6);
    const int lane = threadIdx.x & 63;
    if (wave >= E) return;

    const int r = e0[wave];
    const int c = e1[wave];

    const float w2 = W2[lane];
    // forward direction (r,c): h1pb[r] + h2[c]; reverse (c,r): h1pb[c] + h2[r]
    const float a = h1pb[r * 64 + lane] + h2[c * 64 + lane];
    const float b = h1pb[c * 64 + lane] + h2[r * 64 + lane];
    float p = fmaxf(a, 0.0f) * w2;
    float q = fmaxf(b, 0.0f) * w2;

#pragma unroll
    for (int off = 32; off > 0; off >>= 1) {
        p += __shfl_xor(p, off, 64);
        q += __shfl_xor(q, off, 64);
    }

    if (lane == 0) {
        const float bb    = b2[0];
        const float inv_t = 1.0f / tmp_p[0];
        const float nrc = noise[r * N_NODES + c];
        const float ncr = noise[c * N_NODES + r];
        const float la_rc = p + bb;
        const float la_cr = q + bb;
        const float x1 = (__logf(nrc) - log1pf(-nrc) + la_rc) * inv_t;
        const float x2 = (__logf(ncr) - log1pf(-ncr) + la_cr) * inv_t;
        const float g1 = 1.0f / (1.0f + __expf(-x1));
        const float g2 = 1.0f / (1.0f + __expf(-x2));
        out[wave] = 0.5f * (g1 + g2);
    }
}

extern "C" void kernel_launch(void* const* d_in, const int* in_sizes, int n_in,
                              void* d_out, int out_size, void* d_ws, size_t ws_size,
                              hipStream_t stream) {
    const float* embed = (const float*)d_in[0];
    const int*   eidx  = (const int*)d_in[1];
    const float* noise = (const float*)d_in[2];
    const float* tmp_p = (const float*)d_in[3];
    const float* W1    = (const float*)d_in[4];
    const float* b1    = (const float*)d_in[5];
    const float* W2    = (const float*)d_in[6];
    const float* b2    = (const float*)d_in[7];
    float* out = (float*)d_out;

    const int E = in_sizes[1] / 2;           // edge_index is [2, E]
    const int* e0 = eidx;
    const int* e1 = eidx + E;

    float* h1pb = (float*)d_ws;              // [N_NODES, 64]
    float* h2   = h1pb + N_NODES * 64;       // [N_NODES, 64]

    pg_compute_h<<<N_NODES, 128, 0, stream>>>(embed, W1, b1, h1pb, h2);

    const int threads = 256;                 // 4 waves per block
    const int waves_per_block = threads / 64;
    const int grid = (E + waves_per_block - 1) / waves_per_block;
    pg_edge_kernel<<<grid, threads, 0, stream>>>(e0, e1, noise, tmp_p, W2, b2,
                                                 h1pb, h2, out, E);
}

// Round 2
// 16.279 us; speedup vs baseline: 2.4259x; 2.4259x over previous
//
#include <hip/hip_runtime.h>
#include <cmath>

#define N_NODES 1500

// Kernel 1: h1pb[i,k] = sum_f embed[i,f] * W1[f,k] + b1[k]
//           h2t[i,k]  = sum_f embed[i,f] * W1[64+f,k]
// grid = N_NODES blocks, 128 threads (t<64 -> h1pb column, t>=64 -> h2t column)
__global__ void pg_compute_h(const float* __restrict__ embed,
                             const float* __restrict__ W1,
                             const float* __restrict__ b1,
                             float* __restrict__ h1pb,
                             float* __restrict__ h2t) {
    const int i = blockIdx.x;
    const int t = threadIdx.x;      // 0..127
    const int k = t & 63;
    const int half = t >> 6;

    __shared__ float emb_s[64];
    if (t < 64) emb_s[t] = embed[i * 64 + t];
    __syncthreads();

    const float* wcol = W1 + (half << 6) * 64 + k;   // column k of W1 half
    float a0 = (half == 0) ? b1[k] : 0.0f;
    float a1 = 0.0f, a2 = 0.0f, a3 = 0.0f;
#pragma unroll
    for (int f = 0; f < 64; f += 4) {
        a0 = fmaf(emb_s[f + 0], wcol[(f + 0) * 64], a0);
        a1 = fmaf(emb_s[f + 1], wcol[(f + 1) * 64], a1);
        a2 = fmaf(emb_s[f + 2], wcol[(f + 2) * 64], a2);
        a3 = fmaf(emb_s[f + 3], wcol[(f + 3) * 64], a3);
    }
    const float acc = (a0 + a1) + (a2 + a3);
    if (half == 0) h1pb[i * 64 + k] = acc;
    else           h2t[i * 64 + k]  = acc;
}

// Kernel 2: 4 edges per wave. Quarter q = lane>>4 owns edge (wave*4+q);
// lane l = lane&15 holds hidden dims 4l..4l+3 as float4.
__global__ void pg_edge4(const int* __restrict__ e0,
                         const int* __restrict__ e1,
                         const float* __restrict__ noise,
                         const float* __restrict__ tmp_p,
                         const float* __restrict__ W2,
                         const float* __restrict__ b2,
                         const float4* __restrict__ h1pb4,
                         const float4* __restrict__ h2t4,
                         float* __restrict__ out,
                         int E) {
    const int tid  = blockIdx.x * blockDim.x + threadIdx.x;
    const int wave = tid >> 6;
    const int lane = threadIdx.x & 63;
    const int q    = lane >> 4;     // edge slot within wave
    const int l    = lane & 15;     // float4 slot within 64-dim row

    const int e     = wave * 4 + q;
    const bool valid = (e < E);
    const int ee    = valid ? e : 0;

    const int r = e0[ee];
    const int c = e1[ee];

    // Early noise gather (leader lane per quarter) so HBM/L3 latency overlaps
    // the h-row loads and the reduction below.
    float nrc = 0.5f, ncr = 0.5f;
    if (l == 0) {
        nrc = noise[r * N_NODES + c];
        ncr = noise[c * N_NODES + r];
    }

    const float4 w2v = ((const float4*)W2)[l];

    // forward (r,c): h1pb[r] + h2t[c]; reverse (c,r): h1pb[c] + h2t[r]
    const float4 fa = h1pb4[r * 16 + l];
    const float4 fb = h2t4[c * 16 + l];
    const float4 ra = h1pb4[c * 16 + l];
    const float4 rb = h2t4[r * 16 + l];

    float p = fmaxf(fa.x + fb.x, 0.0f) * w2v.x;
    p = fmaf(fmaxf(fa.y + fb.y, 0.0f), w2v.y, p);
    p = fmaf(fmaxf(fa.z + fb.z, 0.0f), w2v.z, p);
    p = fmaf(fmaxf(fa.w + fb.w, 0.0f), w2v.w, p);

    float s = fmaxf(ra.x + rb.x, 0.0f) * w2v.x;
    s = fmaf(fmaxf(ra.y + rb.y, 0.0f), w2v.y, s);
    s = fmaf(fmaxf(ra.z + rb.z, 0.0f), w2v.z, s);
    s = fmaf(fmaxf(ra.w + rb.w, 0.0f), w2v.w, s);

    // 4-level butterfly within each 16-lane quarter (offsets < 16 stay inside it)
#pragma unroll
    for (int off = 1; off <= 8; off <<= 1) {
        p += __shfl_xor(p, off, 64);
        s += __shfl_xor(s, off, 64);
    }

    if (valid && l == 0) {
        const float bb    = b2[0];
        const float inv_t = 1.0f / tmp_p[0];
        const float la1 = p + bb;
        const float la2 = s + bb;
        const float x1 = (__logf(nrc / (1.0f - nrc)) + la1) * inv_t;
        const float x2 = (__logf(ncr / (1.0f - ncr)) + la2) * inv_t;
        const float g1 = 1.0f / (1.0f + __expf(-x1));
        const float g2 = 1.0f / (1.0f + __expf(-x2));
        out[e] = 0.5f * (g1 + g2);
    }
}

extern "C" void kernel_launch(void* const* d_in, const int* in_sizes, int n_in,
                              void* d_out, int out_size, void* d_ws, size_t ws_size,
                              hipStream_t stream) {
    const float* embed = (const float*)d_in[0];
    const int*   eidx  = (const int*)d_in[1];
    const float* noise = (const float*)d_in[2];
    const float* tmp_p = (const float*)d_in[3];
    const float* W1    = (const float*)d_in[4];
    const float* b1    = (const float*)d_in[5];
    const float* W2    = (const float*)d_in[6];
    const float* b2    = (const float*)d_in[7];
    float* out = (float*)d_out;

    const int E = in_sizes[1] / 2;           // edge_index is [2, E]
    const int* e0 = eidx;
    const int* e1 = eidx + E;

    float* h1pb = (float*)d_ws;              // [N_NODES, 64]
    float* h2t  = h1pb + N_NODES * 64;       // [N_NODES, 64]

    pg_compute_h<<<N_NODES, 128, 0, stream>>>(embed, W1, b1, h1pb, h2t);

    const int edges_per_block = 16;          // 256 threads = 4 waves x 4 edges
    const int grid = (E + edges_per_block - 1) / edges_per_block;
    pg_edge4<<<grid, 256, 0, stream>>>(e0, e1, noise, tmp_p, W2, b2,
                                       (const float4*)h1pb, (const float4*)h2t,
                                       out, E);
}

// Round 3
// 14.099 us; speedup vs baseline: 2.8010x; 1.1546x over previous
//
#include <hip/hip_runtime.h>
#include <hip/hip_bf16.h>
#include <cmath>

#define N_NODES 1500

// Kernel 1: htab[i][k]      = bf16( sum_f embed[i,f]*W1[f,k] + b1[k] )   (h1 + b1)
//           htab[i][64+k]   = bf16( sum_f embed[i,f]*W1[64+f,k] )        (h2)
// grid = N_NODES blocks, 128 threads (t<64 -> h1 column, t>=64 -> h2 column)
__global__ void pg_compute_h(const float* __restrict__ embed,
                             const float* __restrict__ W1,
                             const float* __restrict__ b1,
                             __hip_bfloat16* __restrict__ htab) {
    const int i = blockIdx.x;
    const int t = threadIdx.x;      // 0..127
    const int k = t & 63;
    const int half = t >> 6;

    __shared__ float emb_s[64];
    if (t < 64) emb_s[t] = embed[i * 64 + t];
    __syncthreads();

    const float* wcol = W1 + (half << 6) * 64 + k;   // column k of W1 half
    float a0 = (half == 0) ? b1[k] : 0.0f;
    float a1 = 0.0f, a2 = 0.0f, a3 = 0.0f;
#pragma unroll
    for (int f = 0; f < 64; f += 4) {
        a0 = fmaf(emb_s[f + 0], wcol[(f + 0) * 64], a0);
        a1 = fmaf(emb_s[f + 1], wcol[(f + 1) * 64], a1);
        a2 = fmaf(emb_s[f + 2], wcol[(f + 2) * 64], a2);
        a3 = fmaf(emb_s[f + 3], wcol[(f + 3) * 64], a3);
    }
    const float acc = (a0 + a1) + (a2 + a3);
    htab[i * 128 + half * 64 + k] = __float2bfloat16(acc);
}

// bf16 pair expansion (bf16 -> f32 is a pure bit shift/mask)
__device__ __forceinline__ float blo(unsigned u) {
    union { unsigned i; float f; } v; v.i = u << 16; return v.f;
}
__device__ __forceinline__ float bhi(unsigned u) {
    union { unsigned i; float f; } v; v.i = u & 0xffff0000u; return v.f;
}

// Kernel 2: 8 edges per wave. Group g = lane>>3 owns edge (wave*8+g);
// lane l = lane&7 holds hidden dims 8l..8l+7 (one 16B bf16x8 load per row).
__global__ void pg_edge8(const int* __restrict__ e0,
                         const int* __restrict__ e1,
                         const float* __restrict__ noise,
                         const float* __restrict__ tmp_p,
                         const float* __restrict__ W2,
                         const float* __restrict__ b2,
                         const ushort* __restrict__ htab,
                         float* __restrict__ out,
                         int E) {
    const int tid  = blockIdx.x * blockDim.x + threadIdx.x;
    const int wave = tid >> 6;
    const int lane = threadIdx.x & 63;
    const int g    = lane >> 3;     // edge slot within wave
    const int l    = lane & 7;      // bf16x8 chunk within 128-dim node row

    const int e     = wave * 8 + g;
    const bool valid = (e < E);
    const int ee    = valid ? e : 0;

    const int r = e0[ee];
    const int c = e1[ee];

    // uniform scalars (hoisted so latency overlaps the gathers)
    const float bb    = b2[0];
    const float inv_t = 1.0f / tmp_p[0];

    // noise: lane 0 of each group loads fwd (r,c), lane 1 loads rev (c,r)
    float nv = 0.5f;
    if (l < 2) nv = noise[(l == 0) ? (r * N_NODES + c) : (c * N_NODES + r)];

    // node-interleaved bf16 table: row = 128 bf16 = 16 uint4 (h1: 0..7, h2: 8..15)
    const uint4* hr = (const uint4*)(htab + r * 128);
    const uint4* hc = (const uint4*)(htab + c * 128);
    const uint4 h1r = hr[l];        // h1[r] dims 8l..8l+7
    const uint4 h2r = hr[l + 8];    // h2[r]
    const uint4 h1c = hc[l];        // h1[c]
    const uint4 h2c = hc[l + 8];    // h2[c]

    const float4 w2a = ((const float4*)W2)[l * 2];
    const float4 w2b = ((const float4*)W2)[l * 2 + 1];

    // fwd: relu(h1[r]+h2[c]).w2   rev: relu(h1[c]+h2[r]).w2
    float p = fmaxf(blo(h1r.x) + blo(h2c.x), 0.0f) * w2a.x;
    p = fmaf(fmaxf(bhi(h1r.x) + bhi(h2c.x), 0.0f), w2a.y, p);
    p = fmaf(fmaxf(blo(h1r.y) + blo(h2c.y), 0.0f), w2a.z, p);
    p = fmaf(fmaxf(bhi(h1r.y) + bhi(h2c.y), 0.0f), w2a.w, p);
    p = fmaf(fmaxf(blo(h1r.z) + blo(h2c.z), 0.0f), w2b.x, p);
    p = fmaf(fmaxf(bhi(h1r.z) + bhi(h2c.z), 0.0f), w2b.y, p);
    p = fmaf(fmaxf(blo(h1r.w) + blo(h2c.w), 0.0f), w2b.z, p);
    p = fmaf(fmaxf(bhi(h1r.w) + bhi(h2c.w), 0.0f), w2b.w, p);

    float s = fmaxf(blo(h1c.x) + blo(h2r.x), 0.0f) * w2a.x;
    s = fmaf(fmaxf(bhi(h1c.x) + bhi(h2r.x), 0.0f), w2a.y, s);
    s = fmaf(fmaxf(blo(h1c.y) + blo(h2r.y), 0.0f), w2a.z, s);
    s = fmaf(fmaxf(bhi(h1c.y) + bhi(h2r.y), 0.0f), w2a.w, s);
    s = fmaf(fmaxf(blo(h1c.z) + blo(h2r.z), 0.0f), w2b.x, s);
    s = fmaf(fmaxf(bhi(h1c.z) + bhi(h2r.z), 0.0f), w2b.y, s);
    s = fmaf(fmaxf(blo(h1c.w) + blo(h2r.w), 0.0f), w2b.z, s);
    s = fmaf(fmaxf(bhi(h1c.w) + bhi(h2r.w), 0.0f), w2b.w, s);

    // combined reduction tree: even lanes accumulate p, odd lanes s.
    // level 1 via parity swap (1 shuffle reduces BOTH sums), then xor 2,4.
    const bool odd = (l & 1);
    float w = odd ? s : p;
    float z = odd ? p : s;
    w += __shfl_xor(z, 1, 64);
    w += __shfl_xor(w, 2, 64);
    w += __shfl_xor(w, 4, 64);
    // now l==0: w = sum(p) (fwd), l==1: w = sum(s) (rev)

    float gate = 0.0f;
    if (l < 2) {
        const float x = (__logf(nv / (1.0f - nv)) + w + bb) * inv_t;
        gate = 1.0f / (1.0f + __expf(-x));
    }
    const float gother = __shfl_xor(gate, 1, 64);
    if (valid && l == 0) out[e] = 0.5f * (gate + gother);
}

extern "C" void kernel_launch(void* const* d_in, const int* in_sizes, int n_in,
                              void* d_out, int out_size, void* d_ws, size_t ws_size,
                              hipStream_t stream) {
    const float* embed = (const float*)d_in[0];
    const int*   eidx  = (const int*)d_in[1];
    const float* noise = (const float*)d_in[2];
    const float* tmp_p = (const float*)d_in[3];
    const float* W1    = (const float*)d_in[4];
    const float* b1    = (const float*)d_in[5];
    const float* W2    = (const float*)d_in[6];
    const float* b2    = (const float*)d_in[7];
    float* out = (float*)d_out;

    const int E = in_sizes[1] / 2;           // edge_index is [2, E]
    const int* e0 = eidx;
    const int* e1 = eidx + E;

    __hip_bfloat16* htab = (__hip_bfloat16*)d_ws;   // [N_NODES][128] bf16

    pg_compute_h<<<N_NODES, 128, 0, stream>>>(embed, W1, b1, htab);

    const int edges_per_block = 32;          // 256 threads = 4 waves x 8 edges
    const int grid = (E + edges_per_block - 1) / edges_per_block;
    pg_edge8<<<grid, 256, 0, stream>>>(e0, e1, noise, tmp_p, W2, b2,
                                       (const ushort*)htab, out, E);
}